// Round 14
// baseline (83.259 us; speedup 1.0000x reference)
//
#include <hip/hip_runtime.h>
#include <stdint.h>

#define IN_F   4096
#define OUT_F  11008
#define BATCH  8
#define RPW    2              // output rows per wave (1 wave per block)
#define CHUNK  256            // i-values per chunk (64 lanes * 4 elements)
#define NCHUNK (IN_F/CHUNK)   // 16

#define SBAR() __builtin_amdgcn_sched_barrier(0)

__device__ __forceinline__ float qins_decode(int code, int sgn, float d0, float d1) {
    // |w| = exp2(d0 + code*d1); sign bit straight from the int32 sign (+1 / -1)
    const float e = __builtin_amdgcn_exp2f(fmaf((float)code, d1, d0));
    const uint32_t m = ((uint32_t)sgn) & 0x80000000u;
    return __uint_as_float(__float_as_uint(e) ^ m);
}

// weight loads for chunk K into slot (cc,gg): 8 dwordx4, coalesced
#define LOADW(cc, gg, K)                                                     \
    do {                                                                     \
        const int _ip = (K) * CHUNK + ii0;                                   \
        (cc)[0] = *reinterpret_cast<const int4*>(stored + row0 + _ip);       \
        (cc)[1] = *reinterpret_cast<const int4*>(stored + row1 + _ip);       \
        (gg)[0] = *reinterpret_cast<const int4*>(sign + row0 + _ip);         \
        (gg)[1] = *reinterpret_cast<const int4*>(sign + row1 + _ip);         \
    } while (0)

// x loads for chunk K (8 float4, L1/L2-hot). Issued AFTER the next chunk's
// weight loads are NOT yet issued, and BEFORE this chunk's compute, so the
// compute's x-wait (vmcnt(8)) leaves the weight prefetch in flight.
#define LOADX(xx, K)                                                         \
    do {                                                                     \
        const int _ip = (K) * CHUNK + ii0;                                   \
        _Pragma("unroll")                                                    \
        for (int b = 0; b < BATCH; ++b)                                      \
            (xx)[b] = *reinterpret_cast<const float4*>(x + b * IN_F + _ip);  \
    } while (0)

// pure-register compute: decode 8 weights/lane + 64 FMAs (static indices)
#define COMPUTE(cc, gg, xx)                                                  \
    do {                                                                     \
        float w[RPW][4];                                                     \
        _Pragma("unroll")                                                    \
        for (int r = 0; r < RPW; ++r) {                                      \
            w[r][0] = qins_decode((cc)[r].x, (gg)[r].x, d0, d1);             \
            w[r][1] = qins_decode((cc)[r].y, (gg)[r].y, d0, d1);             \
            w[r][2] = qins_decode((cc)[r].z, (gg)[r].z, d0, d1);             \
            w[r][3] = qins_decode((cc)[r].w, (gg)[r].w, d0, d1);             \
        }                                                                    \
        _Pragma("unroll")                                                    \
        for (int b = 0; b < BATCH; ++b) {                                    \
            _Pragma("unroll")                                                \
            for (int r = 0; r < RPW; ++r) {                                  \
                float a = acc[r][b];                                         \
                a = fmaf(w[r][0], (xx)[b].x, a);                             \
                a = fmaf(w[r][1], (xx)[b].y, a);                             \
                a = fmaf(w[r][2], (xx)[b].z, a);                             \
                a = fmaf(w[r][3], (xx)[b].w, a);                             \
                acc[r][b] = a;                                               \
            }                                                                \
        }                                                                    \
    } while (0)

__global__ __launch_bounds__(64, 2)
void qins_linear_kernel(const float* __restrict__ x,
                        const int*   __restrict__ stored,
                        const int*   __restrict__ sign,
                        const float* __restrict__ log_min,
                        const float* __restrict__ log_max,
                        const float* __restrict__ bias,
                        float* __restrict__ out)
{
    const int lane = threadIdx.x;          // 64 threads = 1 wave
    const int o0   = blockIdx.x * RPW;

    const float lmin = log_min[0];
    const float lmax = log_max[0];
    const float L2E  = 1.44269504088896340736f;
    // log2(|w|) = d0 + code*d1
    const float d1 = -(lmax - lmin) * (L2E / 254.0f);
    const float d0 = (lmin + (lmax - lmin) * (255.0f / 254.0f)) * L2E;

    float acc[RPW][BATCH];
#pragma unroll
    for (int r = 0; r < RPW; ++r)
#pragma unroll
        for (int b = 0; b < BATCH; ++b) acc[r][b] = 0.0f;

    const int ii0  = lane * 4;
    const int row0 = (o0 + 0) * IN_F;
    const int row1 = (o0 + 1) * IN_F;

    // weight double-buffer (32 VGPR) + single x buffer (32 VGPR, short-lived)
    int4   cA[RPW], gA[RPW], cB[RPW], gB[RPW];
    float4 xv[BATCH];

    LOADW(cA, gA, 0);                      // chunk 0 weights in flight
    SBAR();

#pragma unroll 1
    for (int k = 0; k < NCHUNK - 2; k += 2) {
        LOADX(xv, k);                      // x(k): issued after w(k), so
        SBAR();                            //   waiting x(k) retires w(k) only
        LOADW(cB, gB, k + 1);              // w(k+1) prefetch (stays in flight)
        SBAR();
        COMPUTE(cA, gA, xv);               // waits vmcnt(8): w(k+1) survive
        SBAR();
        LOADX(xv, k + 1);
        SBAR();
        LOADW(cA, gA, k + 2);              // w(k+2) prefetch
        SBAR();
        COMPUTE(cB, gB, xv);               // waits vmcnt(8): w(k+2) survive
        SBAR();
    }
    // tail: k = 14,15
    LOADX(xv, NCHUNK - 2);
    SBAR();
    LOADW(cB, gB, NCHUNK - 1);
    SBAR();
    COMPUTE(cA, gA, xv);
    SBAR();
    LOADX(xv, NCHUNK - 1);
    SBAR();
    COMPUTE(cB, gB, xv);

    // butterfly reduction of the 16 (row,batch) partials across the wave
#pragma unroll
    for (int r = 0; r < RPW; ++r)
#pragma unroll
        for (int b = 0; b < BATCH; ++b) {
            float v = acc[r][b];
#pragma unroll
            for (int s = 32; s >= 1; s >>= 1)
                v += __shfl_xor(v, s, 64);
            acc[r][b] = v;
        }

    if (lane == 0) {
#pragma unroll
        for (int r = 0; r < RPW; ++r) {
            const float bv = bias[o0 + r];
#pragma unroll
            for (int b = 0; b < BATCH; ++b)
                out[(size_t)b * OUT_F + o0 + r] = acc[r][b] + bv;
        }
    }
}

extern "C" void kernel_launch(void* const* d_in, const int* in_sizes, int n_in,
                              void* d_out, int out_size, void* d_ws, size_t ws_size,
                              hipStream_t stream)
{
    const float* x      = (const float*)d_in[0];
    const int*   stored = (const int*)d_in[1];
    const int*   sign   = (const int*)d_in[2];
    const float* lmin   = (const float*)d_in[3];
    const float* lmax   = (const float*)d_in[4];
    const float* bias   = (const float*)d_in[5];
    float* out = (float*)d_out;

    dim3 grid(OUT_F / RPW), block(64);
    qins_linear_kernel<<<grid, block, 0, stream>>>(x, stored, sign, lmin, lmax, bias, out);
}

// Round 15
// 78.173 us; speedup vs baseline: 1.0651x; 1.0651x over previous
//
#include <hip/hip_runtime.h>
#include <stdint.h>

#define IN_F   4096
#define OUT_F  11008
#define BATCH  8
#define WAVES  4
#define RPW    2                  // rows per wave
#define RPB    (WAVES*RPW)        // 8 rows per block
#define CHUNK  64                 // i-values per chunk
#define NCHUNK (IN_F/CHUNK)       // 64
#define NSLOT  4                  // ring slots, prefetch depth 3
#define SLOTI  (3*RPB*CHUNK)      // 1536 ints = 6 KB/slot -> 24 KB ring

typedef __attribute__((address_space(1))) const uint32_t* gas_t;
typedef __attribute__((address_space(3))) uint32_t* las_t;

// async global->LDS DMA, 4 B/lane (256 B/request, coalesced). No VGPR
// destination -> regalloc can't sink, spill, or delete the pipeline.
#define DMA4(gsrc, ldst) \
    __builtin_amdgcn_global_load_lds((gas_t)(gsrc), (las_t)(ldst), 4, 0, 0)

#define SBAR() __builtin_amdgcn_sched_barrier(0)
// counted wait: retire exactly the oldest chunk, keep 2 chunks in flight
#define VWAIT(N)                                                             \
    do {                                                                     \
        asm volatile("s_waitcnt vmcnt(" #N ")" ::: "memory");                \
        SBAR();                                                              \
    } while (0)

__device__ __forceinline__ float qins_decode(int code, int sgn, float d0, float d1) {
    // |w| = exp2(d0 + code*d1); sign bit straight from the int32 sign (+1 / -1)
    const float e = __builtin_amdgcn_exp2f(fmaf((float)code, d1, d0));
    const uint32_t m = ((uint32_t)sgn) & 0x80000000u;
    return __uint_as_float(__float_as_uint(e) ^ m);
}

__global__ __launch_bounds__(256, 4)
void qins_linear_kernel(const float* __restrict__ x,
                        const uint32_t* __restrict__ stored,
                        const uint32_t* __restrict__ sign,
                        const float* __restrict__ log_min,
                        const float* __restrict__ log_max,
                        const float* __restrict__ bias,
                        float* __restrict__ out)
{
    // slot (ints): [0,512) stored 8x64 | [512,1024) sign | [1024,1536) x 8x64
    // wave w owns rows/batches {2w, 2w+1}: sub-block [w*128, w*128+128)
    __shared__ int lds[NSLOT][SLOTI];

    const int tid  = threadIdx.x;
    const int lane = tid & 63;
    const int wave = tid >> 6;
    const int o0   = blockIdx.x * RPB;
    const int w128 = wave * 128;

    const float lmin = log_min[0];
    const float lmax = log_max[0];
    const float L2E  = 1.44269504088896340736f;
    // log2(|w|) = d0 + code*d1
    const float d1 = -(lmax - lmin) * (L2E / 254.0f);
    const float d0 = (lmin + (lmax - lmin) * (255.0f / 254.0f)) * L2E;

    // per-lane global source bases (one int per lane per row per chunk)
    const uint32_t* gs0 = stored + (size_t)(o0 + 2 * wave)     * IN_F + lane;
    const uint32_t* gs1 = stored + (size_t)(o0 + 2 * wave + 1) * IN_F + lane;
    const uint32_t* gg0 = sign   + (size_t)(o0 + 2 * wave)     * IN_F + lane;
    const uint32_t* gg1 = sign   + (size_t)(o0 + 2 * wave + 1) * IN_F + lane;
    const uint32_t* gx0 = (const uint32_t*)x + (size_t)(2 * wave)     * IN_F + lane;
    const uint32_t* gx1 = (const uint32_t*)x + (size_t)(2 * wave + 1) * IN_F + lane;

#define ISSUE(T, K)                                                          \
    do {                                                                     \
        const int _ip = (K) * CHUNK;                                         \
        DMA4(gs0 + _ip, &lds[T][w128]);                                      \
        DMA4(gs1 + _ip, &lds[T][w128 + 64]);                                 \
        DMA4(gg0 + _ip, &lds[T][512 + w128]);                                \
        DMA4(gg1 + _ip, &lds[T][512 + w128 + 64]);                           \
        DMA4(gx0 + _ip, &lds[T][1024 + w128]);                               \
        DMA4(gx1 + _ip, &lds[T][1024 + w128 + 64]);                          \
    } while (0)

    float acc[RPW][BATCH];
#pragma unroll
    for (int r = 0; r < RPW; ++r)
#pragma unroll
        for (int b = 0; b < BATCH; ++b) acc[r][b] = 0.0f;

    // prologue: chunks 0,1,2 in flight (18 outstanding DMAs per wave)
    ISSUE(0, 0);
    ISSUE(1, 1);
    ISSUE(2, 2);
    SBAR();

#pragma unroll 1
    for (int k = 0; k < NCHUNK; ++k) {
        // retire exactly chunk k's 6 DMAs; chunks k+1,k+2 stay in flight
        if (k <= NCHUNK - 3)      VWAIT(12);
        else if (k == NCHUNK - 2) VWAIT(6);
        else                      VWAIT(0);
        __builtin_amdgcn_s_barrier();   // raw barrier: no vmcnt(0) drain
        SBAR();

        if (k + 3 < NCHUNK)
            ISSUE((k + 3) & (NSLOT - 1), k + 3);   // refill reclaimed slot
        SBAR();

        // compute chunk k: lane covers one i per row; rows 2w, 2w+1
        {
            const int cur = k & (NSLOT - 1);
            const int c0 = lds[cur][w128 + lane];
            const int c1 = lds[cur][w128 + 64 + lane];
            const int g0 = lds[cur][512 + w128 + lane];
            const int g1 = lds[cur][512 + w128 + 64 + lane];
            const float w0 = qins_decode(c0, g0, d0, d1);
            const float w1 = qins_decode(c1, g1, d0, d1);
#pragma unroll
            for (int b = 0; b < BATCH; ++b) {
                const float xv = __int_as_float(
                    lds[cur][1024 + (b >> 1) * 128 + (b & 1) * 64 + lane]);
                acc[0][b] = fmaf(w0, xv, acc[0][b]);
                acc[1][b] = fmaf(w1, xv, acc[1][b]);
            }
        }
    }

    // butterfly reduction of the 16 (row,batch) partials across the wave
#pragma unroll
    for (int r = 0; r < RPW; ++r)
#pragma unroll
        for (int b = 0; b < BATCH; ++b) {
            float v = acc[r][b];
#pragma unroll
            for (int s = 32; s >= 1; s >>= 1)
                v += __shfl_xor(v, s, 64);
            acc[r][b] = v;
        }

    if (lane == 0) {
#pragma unroll
        for (int r = 0; r < RPW; ++r) {
            const int row = o0 + 2 * wave + r;
            const float bv = bias[row];
#pragma unroll
            for (int b = 0; b < BATCH; ++b)
                out[(size_t)b * OUT_F + row] = acc[r][b] + bv;
        }
    }
#undef ISSUE
}

extern "C" void kernel_launch(void* const* d_in, const int* in_sizes, int n_in,
                              void* d_out, int out_size, void* d_ws, size_t ws_size,
                              hipStream_t stream)
{
    const float*    x      = (const float*)d_in[0];
    const uint32_t* stored = (const uint32_t*)d_in[1];
    const uint32_t* sign   = (const uint32_t*)d_in[2];
    const float*    lmin   = (const float*)d_in[3];
    const float*    lmax   = (const float*)d_in[4];
    const float*    bias   = (const float*)d_in[5];
    float* out = (float*)d_out;

    dim3 grid(OUT_F / RPB), block(WAVES * 64);
    qins_linear_kernel<<<grid, block, 0, stream>>>(x, stored, sign, lmin, lmax, bias, out);
}